// Round 6
// baseline (648.785 us; speedup 1.0000x reference)
//
#include <hip/hip_runtime.h>

// ---------------------------------------------------------------------------
// GatingNetworkWithTopK: h = relu(x@W1+b1); g = softmax(h@W2+b2);
// top-1 mask; out = masked / (colsum+1e-4) * 32768
//
// Numerics: split-bf16 (hi+lo), 3-product MFMA (verified R1-R5: absmax 0.25
// vs threshold 149.76). R6:
//  - de-chained A-split: body kt converts x(kt+2) into the buffer staged for
//    kt+2 (ds_writes get a full body of slack before their barrier guarantee)
//  - 3 register sets (rA/rB/rC) + 3-body unrolled loop -> compile-time LDS
//    buffer offsets (immediate-offset ds_read/ds_write, no rotating pointers)
//  - same W=6 barrier math: 6 vm events/body; barrier at end of body kt
//    guarantees all loads of body kt-1 (order-independent within a body)
// ---------------------------------------------------------------------------

typedef float f32x4 __attribute__((ext_vector_type(4)));
typedef float f32x16 __attribute__((ext_vector_type(16)));
typedef __bf16 bf16x8 __attribute__((ext_vector_type(8)));
typedef unsigned short u16x4 __attribute__((ext_vector_type(4)));
typedef unsigned int u32x4 __attribute__((ext_vector_type(4)));

#define NTOK 32768
#define DIN 1024
#define DH 2048
#define NE 16

__device__ __forceinline__ unsigned short f2bf(float f) {
  unsigned u = __float_as_uint(f);
  u += 0x7FFFu + ((u >> 16) & 1u);
  return (unsigned short)(u >> 16);
}
__device__ __forceinline__ float bf2f(unsigned short s) {
  return __uint_as_float(((unsigned)s) << 16);
}

__device__ __forceinline__ void async16(const void* g, void* s) {
  __builtin_amdgcn_global_load_lds((const __attribute__((address_space(1))) void*)g,
                                   (__attribute__((address_space(3))) void*)s, 16, 0, 0);
}

// 6 vm events per body => vmcnt(6) at a body's end-barrier == "all loads of
// the previous body complete" (order-independent). lgkmcnt(0) drains our
// ds_writes (needed one body later than issued -> full slack).
#define WAIT6_BAR() asm volatile("s_waitcnt vmcnt(6) lgkmcnt(0)\n\ts_barrier" ::: "memory")
#define WAIT0_BAR() asm volatile("s_waitcnt vmcnt(0) lgkmcnt(0)\n\ts_barrier" ::: "memory")

// truncation split of a float pair into packed bf16 hi / lo words.
struct SplitPair { unsigned h, l; };
__device__ __forceinline__ SplitPair split_pair(float a, float b) {
  unsigned ua = __float_as_uint(a), ub = __float_as_uint(b);
  unsigned hab = ua & 0xFFFF0000u, hbb = ub & 0xFFFF0000u;
  float ra = a - __uint_as_float(hab);
  float rb = b - __uint_as_float(hbb);
  SplitPair o;
  o.h = (ua >> 16) | hbb;
  o.l = (__float_as_uint(ra) >> 16) | (__float_as_uint(rb) & 0xFFFF0000u);
  return o;
}

// ------------------- preprocessing: W1 transpose+split, W2 frags ------------
__global__ void prep_k(const float* __restrict__ W1, const float* __restrict__ W2,
                       unsigned short* __restrict__ whi, unsigned short* __restrict__ wlo,
                       unsigned short* __restrict__ w2fh, unsigned short* __restrict__ w2fl) {
  __shared__ float tile[32][33];
  const int b = blockIdx.x;
  if (b < 2048) {
    const int nt = b & 63, kt = b >> 6;
    const int c = threadIdx.x & 31, r0 = threadIdx.x >> 5;
#pragma unroll
    for (int i = 0; i < 4; ++i) {
      int k = (kt << 5) + r0 + (i << 3);
      tile[r0 + (i << 3)][c] = W1[(size_t)k * DH + (nt << 5) + c];
    }
    __syncthreads();
#pragma unroll
    for (int i = 0; i < 4; ++i) {
      int n = (nt << 5) + r0 + (i << 3);
      float vv = tile[c][r0 + (i << 3)];
      unsigned short hh = f2bf(vv);
      whi[(size_t)n * DIN + (kt << 5) + c] = hh;
      wlo[(size_t)n * DIN + (kt << 5) + c] = f2bf(vv - bf2f(hh));
    }
  } else {
    const int t = (b - 2048) * 256 + threadIdx.x;  // 0..4095
    const int kstep = t >> 6, l = t & 63;
    const int q = l >> 4, e = l & 15;
    u16x4 h0, h1, l0, l1;
#pragma unroll
    for (int j = 0; j < 8; ++j) {
      float v = W2[(size_t)((kstep << 5) + (q << 3) + j) * NE + e];
      unsigned short hh = f2bf(v);
      unsigned short ll = f2bf(v - bf2f(hh));
      if (j < 4) { h0[j] = hh; l0[j] = ll; } else { h1[j - 4] = hh; l1[j - 4] = ll; }
    }
    ((u16x4*)w2fh)[t * 2] = h0;
    ((u16x4*)w2fh)[t * 2 + 1] = h1;
    ((u16x4*)w2fl)[t * 2] = l0;
    ((u16x4*)w2fl)[t * 2 + 1] = l1;
  }
}

// ------------------------- fused GEMM1 + partial logits ---------------------
// Block tile 256(tok) x 128(col), 4 waves 2x2, wave tile 128x64. BK=16.
// LDS buffer 24KB = A (256 rows x 64B) + B (128 rows x 64B); row = 4 chunks
// of 16B, stored chunk sc = (lc + (row>>1)) & 3 (all-8-bank-group spread).
// Triple-buffered, compile-time offsets 0 / 24576 / 49152.

struct StgB {
  const unsigned short* gp[2];
  int loff[2];
};

__device__ __forceinline__ void stage_B(const StgB& s, int kt, unsigned char* smem, int bufoff) {
#pragma unroll
  for (int i = 0; i < 2; ++i) async16(s.gp[i] + (kt << 4), smem + bufoff + s.loff[i]);
}

__device__ __forceinline__ void loadA(const float* xrow, int kt, f32x4 (&r)[4]) {
  const f32x4* p = (const f32x4*)(xrow + (kt << 4));
#pragma unroll
  for (int q = 0; q < 4; ++q) r[q] = p[q];
}

__device__ __forceinline__ void convertA(const f32x4 (&r)[4], unsigned char* smem, int bufoff,
                                         int t) {
  unsigned char* arow = smem + bufoff + (t << 6);
  const int t2 = (t >> 1) & 3;
#pragma unroll
  for (int c2 = 0; c2 < 2; ++c2) {
    u32x4 H, L;
    const f32x4 v0 = r[(c2 << 1)];
    const f32x4 v1 = r[(c2 << 1) + 1];
    SplitPair p0 = split_pair(v0[0], v0[1]);
    SplitPair p1 = split_pair(v0[2], v0[3]);
    SplitPair p2 = split_pair(v1[0], v1[1]);
    SplitPair p3 = split_pair(v1[2], v1[3]);
    H[0] = p0.h; L[0] = p0.l;
    H[1] = p1.h; L[1] = p1.l;
    H[2] = p2.h; L[2] = p2.l;
    H[3] = p3.h; L[3] = p3.l;
    const int sc = (c2 + t2) & 3;
    *(u32x4*)(arow + (sc << 4)) = H;
    *(u32x4*)(arow + ((sc ^ 2) << 4)) = L;
  }
}

__device__ __forceinline__ void compute(const unsigned char* smem, int bufoff,
                                        f32x16 (&acc)[4][2], int warow, int wacol, int la,
                                        int half) {
  const unsigned char* sA = smem + bufoff;
  const unsigned char* sB = smem + bufoff + 16384;
  bf16x8 ah[4], al[4], bh[2], bl[2];
#pragma unroll
  for (int u = 0; u < 4; ++u) {
    const int r = warow + (u << 5) + la;
    const int s0 = (half + (r >> 1)) & 3;
    ah[u] = *(const bf16x8*)(sA + (r << 6) + (s0 << 4));
    al[u] = *(const bf16x8*)(sA + (r << 6) + ((s0 ^ 2) << 4));
  }
#pragma unroll
  for (int v = 0; v < 2; ++v) {
    const int r = wacol + (v << 5) + la;
    const int s0 = (half + (r >> 1)) & 3;
    bh[v] = *(const bf16x8*)(sB + (r << 6) + (s0 << 4));
    bl[v] = *(const bf16x8*)(sB + (r << 6) + ((s0 ^ 2) << 4));
  }
#pragma unroll
  for (int i = 0; i < 4; ++i)
#pragma unroll
    for (int j = 0; j < 2; ++j) {
      acc[i][j] = __builtin_amdgcn_mfma_f32_32x32x16_bf16(ah[i], bh[j], acc[i][j], 0, 0, 0);
      acc[i][j] = __builtin_amdgcn_mfma_f32_32x32x16_bf16(ah[i], bl[j], acc[i][j], 0, 0, 0);
      acc[i][j] = __builtin_amdgcn_mfma_f32_32x32x16_bf16(al[i], bh[j], acc[i][j], 0, 0, 0);
    }
}

#define CLAMP63(v) ((v) > 63 ? 63 : (v))

__global__ __launch_bounds__(256, 2) void gemm1_fused_k(
    const float* __restrict__ x, const unsigned short* __restrict__ whi,
    const unsigned short* __restrict__ wlo, const unsigned short* __restrict__ w2fh,
    const unsigned short* __restrict__ w2fl, const float* __restrict__ b1,
    float* __restrict__ plog) {
  __shared__ unsigned char smem[73728];  // 3 x 24576; epilogue reuses [0,34816)
  const int t = threadIdx.x;
  const int w = t >> 6, l = t & 63, la = l & 31, half = l >> 5;
  const int rowBase = blockIdx.y << 8;  // 256 tokens per block
  const int colBase = blockIdx.x << 7;  // 128 cols per block
  const int warow = (w >> 1) << 7;
  const int wacol = (w & 1) << 6;

  StgB s;
#pragma unroll
  for (int i = 0; i < 2; ++i) {
    const int c = (i << 8) + t;  // 0..511
    const int rr = c >> 2, sc = c & 3;
    const int lc = (sc - (rr >> 1)) & 3;
    s.gp[i] = ((lc >> 1) ? wlo : whi) + (size_t)(colBase + rr) * DIN + ((lc & 1) << 3);
    s.loff[i] = 16384 + (c << 4);
  }
  const float* xrow = x + (size_t)(rowBase + t) * DIN;

  f32x16 acc[4][2] = {};
  f32x4 rA[4], rB[4], rC[4];

  // ---- prologue: fill bufs 0,1 with A(0),A(1),B(0),B(1); regs x(2),x(3),x(4)
  loadA(xrow, 0, rA);
  convertA(rA, smem, 0, t);
  loadA(xrow, 1, rA);
  convertA(rA, smem, 24576, t);
  stage_B(s, 0, smem, 0);
  stage_B(s, 1, smem, 24576);
  loadA(xrow, 2, rA);
  loadA(xrow, 3, rB);
  loadA(xrow, 4, rC);
  WAIT0_BAR();

  // body kt: stage B(kt+2) + write A(kt+2) (from reg set kt%3) into buf
  // (kt+2)%3; refill reg set with x(kt+5); compute buf kt%3. 6 vm/body.
#pragma unroll 1
  for (int kt = 0; kt < 63; kt += 3) {
    // body kt   (bufs: compute 0, fill 2)
    stage_B(s, CLAMP63(kt + 2), smem, 49152);
    convertA(rA, smem, 49152, t);
    loadA(xrow, CLAMP63(kt + 5), rA);
    compute(smem, 0, acc, warow, wacol, la, half);
    WAIT6_BAR();
    // body kt+1 (compute 1, fill 0)
    stage_B(s, CLAMP63(kt + 3), smem, 0);
    convertA(rB, smem, 0, t);
    loadA(xrow, CLAMP63(kt + 6), rB);
    compute(smem, 24576, acc, warow, wacol, la, half);
    WAIT6_BAR();
    // body kt+2 (compute 2, fill 1)
    stage_B(s, CLAMP63(kt + 4), smem, 24576);
    convertA(rC, smem, 24576, t);
    loadA(xrow, CLAMP63(kt + 7), rC);
    compute(smem, 49152, acc, warow, wacol, la, half);
    WAIT6_BAR();
  }
  compute(smem, 0, acc, warow, wacol, la, half);  // body 63 (63%3==0)
  WAIT0_BAR();  // drain clamped leftovers before epilogue LDS reuse

  // ---- epilogue: bias + relu (exact fp32 h lives in acc) ----
  float b1v[2];
#pragma unroll
  for (int j = 0; j < 2; ++j) b1v[j] = b1[colBase + wacol + (j << 5) + la];
#pragma unroll
  for (int i = 0; i < 4; ++i)
#pragma unroll
    for (int j = 0; j < 2; ++j)
#pragma unroll
      for (int r = 0; r < 16; ++r) acc[i][j][r] = fmaxf(acc[i][j][r] + b1v[j], 0.0f);

  const int q16 = l >> 4, e16 = l & 15;
  const int myhalf = warow >> 7;

#pragma unroll
  for (int hh = 0; hh < 2; ++hh) {
    f32x4 pacc[2] = {};
#pragma unroll
    for (int p = 0; p < 2; ++p) {
      if (myhalf == hh) {
#pragma unroll
        for (int i = 0; i < 4; ++i)
#pragma unroll
          for (int j = 0; j < 2; ++j)
#pragma unroll
            for (int r = 0; r < 16; ++r) {
              const int rowl = (i << 5) + (r & 3) + ((r >> 2) << 3) + (half << 2);
              const int coll = wacol + (j << 5) + la;
              const float v = acc[i][j][r];
              const unsigned short sv = (p == 0) ? f2bf(v) : f2bf(v - bf2f(f2bf(v)));
              *(unsigned short*)(smem + rowl * 272 + (coll << 1)) = sv;
            }
      }
      __syncthreads();
#pragma unroll
      for (int tm = 0; tm < 2; ++tm) {
        const int tokl = ((w * 2 + tm) << 4) + e16;  // 0..127
#pragma unroll
        for (int ss = 0; ss < 4; ++ss) {
          bf16x8 a = *(const bf16x8*)(smem + tokl * 272 + (ss << 6) + (q16 << 4));
          const size_t gs = (size_t)(((colBase >> 5) + ss) << 6);
          bf16x8 vbh = *(const bf16x8*)(w2fh + ((gs + l) << 3));
          pacc[tm] = __builtin_amdgcn_mfma_f32_16x16x32_bf16(a, vbh, pacc[tm], 0, 0, 0);
          if (p == 0) {
            bf16x8 vbl = *(const bf16x8*)(w2fl + ((gs + l) << 3));
            pacc[tm] = __builtin_amdgcn_mfma_f32_16x16x32_bf16(a, vbl, pacc[tm], 0, 0, 0);
          }
        }
      }
      __syncthreads();
    }
#pragma unroll
    for (int tm = 0; tm < 2; ++tm)
#pragma unroll
      for (int r = 0; r < 4; ++r) {
        const int tokl = (hh << 7) + (((w * 2 + tm) << 4)) + (q16 << 2) + r;
        plog[((size_t)blockIdx.x << 19) + ((size_t)(rowBase + tokl) << 4) + e16] = pacc[tm][r];
      }
  }
}

// ----------------- reduce partials + softmax + argmax + denom ---------------
__global__ void reduce_softmax_k(const float* __restrict__ plog, const float* __restrict__ b2,
                                 int* __restrict__ top1, float* __restrict__ pval,
                                 float* __restrict__ denom) {
  const int tok = blockIdx.x * 256 + threadIdx.x;
  float lg[16];
#pragma unroll
  for (int e = 0; e < 16; ++e) lg[e] = b2[e];
  for (int p = 0; p < 16; ++p) {
    const f32x4* q = (const f32x4*)(plog + ((size_t)p << 19) + ((size_t)tok << 4));
#pragma unroll
    for (int g = 0; g < 4; ++g) {
      f32x4 v = q[g];
      lg[g * 4 + 0] += v[0];
      lg[g * 4 + 1] += v[1];
      lg[g * 4 + 2] += v[2];
      lg[g * 4 + 3] += v[3];
    }
  }
  float m = lg[0];
  int idx = 0;
#pragma unroll
  for (int e = 1; e < 16; ++e)
    if (lg[e] > m) { m = lg[e]; idx = e; }
  float se = 0.0f;
#pragma unroll
  for (int e = 0; e < 16; ++e) se += expf(lg[e] - m);
  const float pt = 1.0f / se;

  __shared__ float sden[16];
  if (threadIdx.x < 16) sden[threadIdx.x] = 0.0f;
  __syncthreads();
  atomicAdd(&sden[idx], pt);
  __syncthreads();
  if (threadIdx.x < 16) atomicAdd(&denom[threadIdx.x], sden[threadIdx.x]);
  top1[tok] = idx;
  pval[tok] = pt;
}

// ------------------------------- finalize -----------------------------------
__global__ void finalize_k(const int* __restrict__ top1, const float* __restrict__ pval,
                           const float* __restrict__ denom, float* __restrict__ out) {
  const int tok = blockIdx.x * 256 + threadIdx.x;
  const int e0 = top1[tok];
  const float v = pval[tok] / (denom[e0] + 1e-4f) * 32768.0f;
  f32x4* q = (f32x4*)(out + ((size_t)tok << 4));
#pragma unroll
  for (int g = 0; g < 4; ++g) {
    f32x4 o;
#pragma unroll
    for (int j = 0; j < 4; ++j) o[j] = ((g * 4 + j) == e0) ? v : 0.0f;
    q[g] = o;
  }
}

// ---------------------------------------------------------------------------
extern "C" void kernel_launch(void* const* d_in, const int* in_sizes, int n_in, void* d_out,
                              int out_size, void* d_ws, size_t ws_size, hipStream_t stream) {
  (void)in_sizes; (void)n_in; (void)out_size; (void)ws_size;
  const float* x = (const float*)d_in[0];
  const float* W1 = (const float*)d_in[1];
  const float* b1 = (const float*)d_in[2];
  const float* W2 = (const float*)d_in[3];
  const float* b2 = (const float*)d_in[4];
  float* out = (float*)d_out;

  char* p = (char*)d_ws;
  unsigned short* whi = (unsigned short*)p; p += (size_t)DH * DIN * 2;
  unsigned short* wlo = (unsigned short*)p; p += (size_t)DH * DIN * 2;
  unsigned short* w2fh = (unsigned short*)p; p += (size_t)64 * 64 * 8 * 2;
  unsigned short* w2fl = (unsigned short*)p; p += (size_t)64 * 64 * 8 * 2;
  float* plog = (float*)p; p += (size_t)16 * NTOK * NE * 4;
  int* top1 = (int*)p; p += (size_t)NTOK * 4;
  float* pval = (float*)p; p += (size_t)NTOK * 4;
  float* denom = (float*)p; p += 256;

  (void)hipMemsetAsync(denom, 0, 256, stream);
  prep_k<<<2064, 256, 0, stream>>>(W1, W2, whi, wlo, w2fh, w2fl);
  gemm1_fused_k<<<dim3(16, 128), 256, 0, stream>>>(x, whi, wlo, w2fh, w2fl, b1, plog);
  reduce_softmax_k<<<128, 256, 0, stream>>>(plog, b2, top1, pval, denom);
  finalize_k<<<128, 256, 0, stream>>>(top1, pval, denom, out);
}